// Round 12
// baseline (7616.552 us; speedup 1.0000x reference)
//
#include <hip/hip_runtime.h>
#include <hip/hip_bf16.h>
#include <hip/hip_fp16.h>

// GAT 2-layer forward. N=50000, E=800000 (+N self loops).
// L1: 128 -> 4x64 concat 256, ReLU.  L2: 256 -> 128, ReLU.
// R1: fused CSR softmax+aggregate.  R8: fp16 MFMA GEMMs.  R5: att_dots in
// GEMM epilogue.  R6: 4 nodes/256-thd agg.  R10: atomic-free CSR fill.
// R11: WHOLE pipeline in ONE kernel via dynamic-block-id phase chaining
// (decoupled-lookback safety argument: logical id = scheduling order via
// atomic counter; a block only spins on counters published by smaller ids,
// which are done or resident -> no deadlock, no cooperative launch).
// Phases: zero -> prep -> scan -> {fill || gemm1} -> agg1 -> gemm2 -> agg2.
// Gates = __threadfence + agent-scope counters (G12/G16). 8 dispatches -> 2.

#define NEG_SLOPE 0.2f

typedef __attribute__((ext_vector_type(8))) _Float16 f16x8;  // 8 fp16 = 4 VGPRs
typedef __attribute__((ext_vector_type(8))) short s16x8;
typedef __attribute__((ext_vector_type(4))) float f32x4;

// 16B load of 8 fp16 -> 8 fp32
__device__ inline void loadH8(float* v, const __half* p) {
    union { s16x8 raw; __half2 h2[4]; } u;
    u.raw = *(const s16x8*)p;
#pragma unroll
    for (int i = 0; i < 4; ++i) {
        float2 f = __half22float2(u.h2[i]);
        v[2 * i] = f.x;
        v[2 * i + 1] = f.y;
    }
}

// ---------------- phase gates ----------------

__device__ inline void phase_done(int* c) {
    __syncthreads();
    __threadfence();                      // device-scope: prior writes visible
    if (threadIdx.x == 0)
        __hip_atomic_fetch_add(c, 1, __ATOMIC_RELEASE, __HIP_MEMORY_SCOPE_AGENT);
}

__device__ inline void phase_wait(int* c, int target) {
    if (threadIdx.x == 0) {
        while (__hip_atomic_load(c, __ATOMIC_ACQUIRE, __HIP_MEMORY_SCOPE_AGENT) < target)
            __builtin_amdgcn_s_sleep(8);
    }
    __syncthreads();
    __threadfence();                      // acquire for all threads of block
}

// ---------------- W pack: B-frag (16x16x32) lane layout ----------------
// lane l holds B[k0 + (l>>4)*8 + j][n0 + (l&15)], j=0..7.

__device__ inline void pack_w_elem(const float* __restrict__ W, __half* __restrict__ bp,
                                   int K, int N, int tid) {
    int k = tid / N, n = tid - k * N;
    int ks = k >> 5, k5 = k & 31, quad = k5 >> 3, j = k5 & 7;
    int ct = n >> 4;
    int lane = quad * 16 + (n & 15);
    size_t idx = ((size_t)(ct * (K >> 5) + ks) * 64 + lane) * 8 + j;
    bp[idx] = __float2half(W[tid]);
}

// ---------------- scan body (decoupled lookback, bid = logical id) ----------

__device__ void scan_body(int bid, const int* __restrict__ cnt, int* __restrict__ row_start,
                          unsigned long long* __restrict__ status, int N, int nb) {
    __shared__ int sm[256];
    __shared__ int sprefix;
    int t = threadIdx.x;
    int i = bid * 256 + t;
    int c = (i < N) ? cnt[i] : 0;
    sm[t] = c;
    __syncthreads();
    for (int off = 1; off < 256; off <<= 1) {
        int v = (t >= off) ? sm[t - off] : 0;
        __syncthreads();
        sm[t] += v;
        __syncthreads();
    }
    int incl = sm[t];
    int aggregate = sm[255];
    if (t == 0) {
        unsigned long long pub = (bid == 0)
            ? (((unsigned long long)aggregate << 2) | 2ull)
            : (((unsigned long long)aggregate << 2) | 1ull);
        __hip_atomic_store(&status[bid], pub, __ATOMIC_RELEASE, __HIP_MEMORY_SCOPE_AGENT);
        int prefix = 0;
        if (bid > 0) {
            int j = bid - 1;
            while (true) {
                unsigned long long s =
                    __hip_atomic_load(&status[j], __ATOMIC_ACQUIRE, __HIP_MEMORY_SCOPE_AGENT);
                unsigned long long f = s & 3ull;
                if (f == 0ull) continue;
                prefix += (int)(s >> 2);
                if (f == 2ull) break;
                --j;
            }
            __hip_atomic_store(&status[bid],
                (((unsigned long long)(prefix + aggregate)) << 2) | 2ull,
                __ATOMIC_RELEASE, __HIP_MEMORY_SCOPE_AGENT);
        }
        sprefix = prefix;
    }
    __syncthreads();
    int base = sprefix;
    if (i < N) row_start[i] = base + incl - c;
    if (bid == nb - 1 && t == 255) row_start[N] = base + aggregate;
}

// ---------------- fp16 MFMA GEMM body + fused attention dots ---------------

template<int K, int NN, int H, bool ATOMIC>
__device__ void gemm_body(int bx, int M,
        const __half* __restrict__ A, const __half* __restrict__ Bp,
        const float* __restrict__ att_s, const float* __restrict__ att_d,
        float* __restrict__ as_, float* __restrict__ ad_,
        __half* __restrict__ Hout) {
    constexpr int KS = K >> 5;
    constexpr int CW = NN / 64;            // waves across columns
    constexpr int RW = 4 / CW;             // row-wave groups per block
    constexpr int C = NN / H;              // channels per head
    const int lane = threadIdx.x & 63;
    const int w = threadIdx.x >> 6;
    const int wr = w / CW;
    const int wc = w % CW;
    const int quad = lane >> 4;
    const int r16 = lane & 15;
    const int mBase = bx * (RW * 32) + wr * 32;
    const int nBase = wc * 64;
    const int head = nBase / C;

    f32x4 acc[2][4];
#pragma unroll
    for (int rt = 0; rt < 2; ++rt)
#pragma unroll
        for (int ct = 0; ct < 4; ++ct) acc[rt][ct] = (f32x4){0.f, 0.f, 0.f, 0.f};

#pragma unroll
    for (int ks = 0; ks < KS; ++ks) {
        f16x8 af[2];
#pragma unroll
        for (int rt = 0; rt < 2; ++rt) {
            int row = mBase + rt * 16 + r16;
            if (row < M) {
                size_t off = (size_t)row * K + ks * 32 + quad * 8;
                af[rt] = *(const f16x8*)(A + off);
            } else {
                af[rt] = (f16x8){0,0,0,0,0,0,0,0};
            }
        }
        f16x8 bf[4];
#pragma unroll
        for (int ct = 0; ct < 4; ++ct) {
            int ctg = (nBase >> 4) + ct;
            size_t off = ((size_t)(ctg * KS + ks) * 64 + lane) * 8;
            bf[ct] = *(const f16x8*)(Bp + off);
        }
#pragma unroll
        for (int rt = 0; rt < 2; ++rt)
#pragma unroll
            for (int ct = 0; ct < 4; ++ct)
                acc[rt][ct] = __builtin_amdgcn_mfma_f32_16x16x32_f16(af[rt], bf[ct], acc[rt][ct], 0, 0, 0);
    }

    // store h (fp16); C/D layout: lane l reg r -> row=(l>>4)*4+r, col=l&15
#pragma unroll
    for (int rt = 0; rt < 2; ++rt)
#pragma unroll
        for (int ct = 0; ct < 4; ++ct) {
            int row0 = mBase + rt * 16 + quad * 4;
            int col = nBase + ct * 16 + r16;
#pragma unroll
            for (int r = 0; r < 4; ++r) {
                int row = row0 + r;
                if (row < M) Hout[(size_t)row * NN + col] = __float2half(acc[rt][ct][r]);
            }
        }

    // fused attention dots
    float attS[4], attD[4];
#pragma unroll
    for (int ct = 0; ct < 4; ++ct) {
        int cc = (nBase % C) + ct * 16 + r16;   // channel within head
        attS[ct] = att_s[head * C + cc];
        attD[ct] = att_d[head * C + cc];
    }
#pragma unroll
    for (int rt = 0; rt < 2; ++rt)
#pragma unroll
        for (int r = 0; r < 4; ++r) {
            float ps = 0.f, pd = 0.f;
#pragma unroll
            for (int ct = 0; ct < 4; ++ct) {
                ps += acc[rt][ct][r] * attS[ct];
                pd += acc[rt][ct][r] * attD[ct];
            }
#pragma unroll
            for (int off = 1; off < 16; off <<= 1) {
                ps += __shfl_xor(ps, off);
                pd += __shfl_xor(pd, off);
            }
            int row = mBase + rt * 16 + quad * 4 + r;
            if (r16 == 0 && row < M) {
                if (ATOMIC) {
                    atomicAdd(&as_[row * H + head], ps);
                    atomicAdd(&ad_[row * H + head], pd);
                } else {
                    as_[row * H + head] = ps;
                    ad_[row * H + head] = pd;
                }
            }
        }
}

// ---------------- fused CSR softmax + aggregate body (fp16 gather) ----------

__device__ inline float edge_w(float a) {
    float e = a > 0.f ? a : NEG_SLOPE * a;
    return __expf(e);
}

template<int U, int HC, int H, int GRP>
__device__ inline void agg_step(int p, const int* __restrict__ csr_src,
                                const __half* __restrict__ h,
                                const float* __restrict__ as_, float adv,
                                int c0, int head, float* acc, float& den) {
    int srcv[U];
#pragma unroll
    for (int u = 0; u < U; ++u) srcv[u] = csr_src[p + u * GRP];
    float f[U][8];
#pragma unroll
    for (int u = 0; u < U; ++u) loadH8(f[u], h + (size_t)srcv[u] * HC + c0);
    float wv[U];
#pragma unroll
    for (int u = 0; u < U; ++u) wv[u] = edge_w(as_[srcv[u] * H + head] + adv);
#pragma unroll
    for (int u = 0; u < U; ++u) den += wv[u];
#pragma unroll
    for (int u = 0; u < U; ++u)
#pragma unroll
        for (int i = 0; i < 8; ++i) acc[i] += wv[u] * f[u][i];
}

template<int HC, int H, bool F16OUT>
__device__ void agg_body(int bx, int N,
                         const int* __restrict__ row_start,
                         const int* __restrict__ csr_src,
                         const __half* __restrict__ h,
                         const float* __restrict__ as_,
                         const float* __restrict__ ad_,
                         const float* __restrict__ bias,
                         float* __restrict__ out,
                         __half* __restrict__ outh) {
    constexpr int LPE = HC / 8;          // lanes per edge (32 or 16)
    constexpr int GRP = 64 / LPE;        // concurrent edges per wave (2 or 4)
    constexpr int C = HC / H;
    const int n = bx * 4 + (threadIdx.x >> 6);
    if (n >= N) return;
    const int lane = threadIdx.x & 63;
    const int g = lane / LPE;
    const int lq = lane % LPE;
    const int c0 = lq * 8;
    const int head = c0 / C;
    const int s0 = row_start[n], s1 = row_start[n + 1];
    const float adv = ad_[n * H + head];
    float acc[8] = {};
    float den = 0.f;
    int p = s0 + g;
    for (; p + 3 * GRP < s1; p += 4 * GRP)
        agg_step<4, HC, H, GRP>(p, csr_src, h, as_, adv, c0, head, acc, den);
    for (; p < s1; p += GRP)
        agg_step<1, HC, H, GRP>(p, csr_src, h, as_, adv, c0, head, acc, den);
#pragma unroll
    for (int off = LPE; off < 64; off <<= 1) {
        den += __shfl_xor(den, off);
#pragma unroll
        for (int i = 0; i < 8; ++i) acc[i] += __shfl_xor(acc[i], off);
    }
    if (g == 0) {
        float dinv = 1.0f / (den + 1e-16f);
        float o[8];
#pragma unroll
        for (int i = 0; i < 8; ++i) {
            float v = acc[i] * dinv + bias[c0 + i];
            o[i] = v > 0.f ? v : 0.f;
        }
        if (F16OUT) {
            union { s16x8 raw; __half hv[8]; } u;
#pragma unroll
            for (int i = 0; i < 8; ++i) u.hv[i] = __float2half(o[i]);
            *(s16x8*)(outh + (size_t)n * HC + c0) = u.raw;
        } else {
            float4 v0 = make_float4(o[0], o[1], o[2], o[3]);
            float4 v1 = make_float4(o[4], o[5], o[6], o[7]);
            *(float4*)(out + (size_t)n * HC + c0) = v0;
            *(float4*)(out + (size_t)n * HC + c0 + 4) = v1;
        }
    }
}

// ---------------- the mega kernel ----------------
// counters: [0]=gid [1]=zero [2]=prep [3]=scan [4]=fill [5]=gemm1 [6]=agg1
//           [7]=gemm2   (pre-zeroed by a 32B memset)

__global__ __launch_bounds__(256) void mega_kernel(
        int* __restrict__ counters,
        int ZB, int PB, int SB, int FB, int G1B, int A1B, int G2B,
        int* __restrict__ zeroBase, int zeroWords,
        const float* __restrict__ x, __half* __restrict__ xf, int nx,
        const float* __restrict__ W1, __half* __restrict__ bp1,
        const float* __restrict__ W2, __half* __restrict__ bp2,
        const int* __restrict__ ei, int E, int N,
        int* __restrict__ cnt, int* __restrict__ rank,
        int* __restrict__ row_start, unsigned long long* __restrict__ status,
        int* __restrict__ csr_src,
        const float* __restrict__ att_s1, const float* __restrict__ att_d1,
        float* __restrict__ as1, float* __restrict__ ad1,
        const float* __restrict__ att_s2, const float* __restrict__ att_d2,
        float* __restrict__ as2, float* __restrict__ ad2,
        __half* __restrict__ h1, __half* __restrict__ x2,
        const float* __restrict__ b1, const float* __restrict__ b2,
        float* __restrict__ out) {
    __shared__ int sid;
    if (threadIdx.x == 0)
        sid = __hip_atomic_fetch_add(&counters[0], 1, __ATOMIC_RELAXED,
                                     __HIP_MEMORY_SCOPE_AGENT);
    __syncthreads();
    int id = sid;
    const int t = threadIdx.x;

    if (id < ZB) {                       // ---- phase: zero cnt|as2|ad2|status
        int base = id * 1024 + t;
#pragma unroll
        for (int i = 0; i < 4; ++i) {
            int w = base + i * 256;
            if (w < zeroWords) zeroBase[w] = 0;
        }
        phase_done(&counters[1]);
        return;
    }
    id -= ZB;

    if (id < PB) {                       // ---- phase: prep (convert/pack/count)
        phase_wait(&counters[1], ZB);
        int base = id * 3328;
        int Etot = E + N;
        for (int i = 0; i < 13; ++i) {
            int tid = base + i * 256 + t;
            if (tid < nx) xf[tid] = __float2half(x[tid]);
            if (tid < Etot) {
                int d = (tid < E) ? ei[E + tid] : (tid - E);
                rank[tid] = atomicAdd(&cnt[d], 1);
            }
            if (tid < 32768) {
                pack_w_elem(W1, bp1, 128, 256, tid);
                pack_w_elem(W2, bp2, 256, 128, tid);
            }
        }
        phase_done(&counters[2]);
        return;
    }
    id -= PB;

    if (id < SB) {                       // ---- phase: scan (lookback)
        phase_wait(&counters[2], PB);
        scan_body(id, cnt, row_start, status, N, SB);
        phase_done(&counters[3]);
        return;
    }
    id -= SB;

    if (id < FB) {                       // ---- phase: atomic-free fill
        phase_wait(&counters[3], SB);
        int e = id * 256 + t;
        int Etot = E + N;
        if (e < Etot) {
            int s, d;
            if (e < E) { s = ei[e]; d = ei[E + e]; } else { s = e - E; d = s; }
            csr_src[row_start[d] + rank[e]] = s;
        }
        phase_done(&counters[4]);
        return;
    }
    id -= FB;

    if (id < G1B) {                      // ---- phase: gemm1 (overlaps fill)
        phase_wait(&counters[2], PB);    // needs prep only
        gemm_body<128, 256, 4, false>(id, N, xf, bp1, att_s1, att_d1, as1, ad1, h1);
        phase_done(&counters[5]);
        return;
    }
    id -= G1B;

    if (id < A1B) {                      // ---- phase: agg1
        phase_wait(&counters[4], FB);
        phase_wait(&counters[5], G1B);
        agg_body<256, 4, true>(id, N, row_start, csr_src, h1, as1, ad1, b1,
                               nullptr, x2);
        phase_done(&counters[6]);
        return;
    }
    id -= A1B;

    if (id < G2B) {                      // ---- phase: gemm2 (h2 = h1 reuse)
        phase_wait(&counters[6], A1B);
        gemm_body<256, 128, 1, true>(id, N, x2, bp2, att_s2, att_d2, as2, ad2, h1);
        phase_done(&counters[7]);
        return;
    }
    id -= G2B;

    {                                    // ---- phase: agg2 -> out
        phase_wait(&counters[7], G2B);
        agg_body<128, 1, false>(id, N, row_start, csr_src, h1, as2, ad2, b2,
                                out, nullptr);
    }
}

extern "C" void kernel_launch(void* const* d_in, const int* in_sizes, int n_in,
                              void* d_out, int out_size, void* d_ws, size_t ws_size,
                              hipStream_t stream) {
    const float* x      = (const float*)d_in[0];
    const int*   ei     = (const int*)d_in[1];
    const float* W1     = (const float*)d_in[2];
    const float* att_s1 = (const float*)d_in[3];
    const float* att_d1 = (const float*)d_in[4];
    const float* b1     = (const float*)d_in[5];
    const float* W2     = (const float*)d_in[6];
    const float* att_s2 = (const float*)d_in[7];
    const float* att_d2 = (const float*)d_in[8];
    const float* b2     = (const float*)d_in[9];
    float* out = (float*)d_out;

    const int N_ = in_sizes[0] / 128;   // 50000
    const int E_ = in_sizes[1] / 2;     // 800000
    const int Etot = E_ + N_;           // 850000

    // workspace layout
    __half* h1 = (__half*)d_ws;                              // N*256 fp16 (also h2)
    __half* x2 = h1 + (size_t)N_ * 256;                      // N*256 fp16
    __half* xf = x2;                                         // N*128 fp16 (overlay:
                                                             // xf dead before agg1 writes x2)
    __half* bp1 = x2 + (size_t)N_ * 256;                     // 32768 fp16
    __half* bp2 = bp1 + 32768;                               // 32768 fp16
    float* as1 = (float*)(bp2 + 32768);                      // N*4
    float* ad1 = as1 + (size_t)N_ * 4;                       // N*4
    int* counters = (int*)(ad1 + (size_t)N_ * 4);            // 8 ints (memset)
    // ---- in-kernel zero region: cnt | as2 | ad2 | status (3N + 512 words)
    int*   cnt    = counters + 8;                            // N
    float* as2    = (float*)(cnt + N_);                      // N
    float* ad2    = as2 + N_;                                // N
    unsigned long long* status = (unsigned long long*)(ad2 + N_);  // 256
    int zeroWords = 3 * N_ + 512;
    // ---- end zero region
    int* row_start = (int*)(status + 256);                   // N+1
    int* rank      = row_start + (N_ + 1);                   // Etot
    int* csr_src   = rank + Etot;                            // Etot

    int nx = N_ * 128;
    int ZB  = (zeroWords + 1023) / 1024;   // 147
    int PB  = (nx + 3327) / 3328;          // 1924
    int SB  = (N_ + 255) / 256;            // 196
    int FB  = (Etot + 255) / 256;          // 3321
    int G1B = (N_ + 31) / 32;              // 1563
    int A1B = (N_ + 3) / 4;                // 12500
    int G2B = (N_ + 63) / 64;              // 782
    int A2B = (N_ + 3) / 4;                // 12500
    int grid = ZB + PB + SB + FB + G1B + A1B + G2B + A2B;    // 32933

    hipMemsetAsync(counters, 0, 8 * sizeof(int), stream);
    mega_kernel<<<grid, 256, 0, stream>>>(
        counters, ZB, PB, SB, FB, G1B, A1B, G2B,
        cnt, zeroWords,
        x, xf, nx, W1, bp1, W2, bp2, ei, E_, N_,
        cnt, rank, row_start, status, csr_src,
        att_s1, att_d1, as1, ad1, att_s2, att_d2, as2, ad2,
        h1, x2, b1, b2, out);

    (void)n_in; (void)out_size; (void)ws_size;
}

// Round 13
// 318.210 us; speedup vs baseline: 23.9356x; 23.9356x over previous
//
#include <hip/hip_runtime.h>
#include <hip/hip_bf16.h>
#include <hip/hip_fp16.h>

// GAT 2-layer forward. N=50000, E=800000 (+N self loops).
// L1: 128 -> 4x64 concat 256, ReLU.  L2: 256 -> 128, ReLU.
// R1: fused CSR softmax+aggregate.  R8: fp16 MFMA GEMMs.  R5: att_dots in
// GEMM epilogue.  R6: 4 nodes/256-thd agg.  R10: atomic-free CSR fill.
// R11 mega-kernel REVERTED (same-address device-scope atomic contention:
// ~33K phase RMWs + ~2K spinning waiters on a few cache lines -> 23x slower).
// R12: fill+gemm1 fused as disjoint block ranges -- safe NOW because R10's
// fill has no atomic round-trip (R9's failure mechanism); saves one dispatch
// gap and overlaps scatter latency with MFMA.

#define NEG_SLOPE 0.2f

typedef __attribute__((ext_vector_type(8))) _Float16 f16x8;  // 8 fp16 = 4 VGPRs
typedef __attribute__((ext_vector_type(8))) short s16x8;
typedef __attribute__((ext_vector_type(4))) float f32x4;

// 16B load of 8 fp16 -> 8 fp32
__device__ inline void loadH8(float* v, const __half* p) {
    union { s16x8 raw; __half2 h2[4]; } u;
    u.raw = *(const s16x8*)p;
#pragma unroll
    for (int i = 0; i < 4; ++i) {
        float2 f = __half22float2(u.h2[i]);
        v[2 * i] = f.x;
        v[2 * i + 1] = f.y;
    }
}

// ---------------- fused prep: x->fp16, pack W1/W2, count degrees + ranks ----
// (cnt / as2 / ad2 / status / bcount zeroed by one prior hipMemsetAsync)
// B-frag (16x16x32): lane l holds B[k0 + (l>>4)*8 + j][n0 + (l&15)], j=0..7.

__device__ inline void pack_w_elem(const float* __restrict__ W, __half* __restrict__ bp,
                                   int K, int N, int tid) {
    int k = tid / N, n = tid - k * N;
    int ks = k >> 5, k5 = k & 31, quad = k5 >> 3, j = k5 & 7;
    int ct = n >> 4;
    int lane = quad * 16 + (n & 15);
    size_t idx = ((size_t)(ct * (K >> 5) + ks) * 64 + lane) * 8 + j;
    bp[idx] = __float2half(W[tid]);
}

__global__ __launch_bounds__(256) void prep_kernel(
        const float* __restrict__ x, __half* __restrict__ xf, int nx,
        const float* __restrict__ W1, __half* __restrict__ bp1,
        const float* __restrict__ W2, __half* __restrict__ bp2,
        const int* __restrict__ ei, int E, int* __restrict__ cnt,
        int* __restrict__ rank, int N) {
    int tid = blockIdx.x * blockDim.x + threadIdx.x;
    if (tid < nx) xf[tid] = __float2half(x[tid]);
    int Etot = E + N;
    if (tid < Etot) {
        int d = (tid < E) ? ei[E + tid] : (tid - E);
        rank[tid] = atomicAdd(&cnt[d], 1);    // coalesced store of atomic return
    }
    if (tid < 128 * 256) pack_w_elem(W1, bp1, 128, 256, tid);
    if (tid < 256 * 128) pack_w_elem(W2, bp2, 256, 128, tid);
}

// ---------------- single-kernel chained scan (decoupled lookback) ----------

__global__ __launch_bounds__(256) void scan_chained(
        const int* __restrict__ cnt, int* __restrict__ row_start,
        unsigned long long* __restrict__ status,
        int* __restrict__ bcount, int N, int nb) {
    __shared__ int sm[256];
    __shared__ int sbid;
    __shared__ int sprefix;
    int t = threadIdx.x;
    if (t == 0) sbid = atomicAdd(bcount, 1);
    __syncthreads();
    const int bid = sbid;
    int i = bid * 256 + t;
    int c = (i < N) ? cnt[i] : 0;
    sm[t] = c;
    __syncthreads();
    for (int off = 1; off < 256; off <<= 1) {
        int v = (t >= off) ? sm[t - off] : 0;
        __syncthreads();
        sm[t] += v;
        __syncthreads();
    }
    int incl = sm[t];
    int aggregate = sm[255];
    if (t == 0) {
        unsigned long long pub = (bid == 0)
            ? (((unsigned long long)aggregate << 2) | 2ull)
            : (((unsigned long long)aggregate << 2) | 1ull);
        __hip_atomic_store(&status[bid], pub, __ATOMIC_RELEASE, __HIP_MEMORY_SCOPE_AGENT);
        int prefix = 0;
        if (bid > 0) {
            int j = bid - 1;
            while (true) {
                unsigned long long s =
                    __hip_atomic_load(&status[j], __ATOMIC_ACQUIRE, __HIP_MEMORY_SCOPE_AGENT);
                unsigned long long f = s & 3ull;
                if (f == 0ull) continue;       // not published yet, spin
                prefix += (int)(s >> 2);
                if (f == 2ull) break;          // hit an inclusive entry
                --j;
            }
            __hip_atomic_store(&status[bid],
                (((unsigned long long)(prefix + aggregate)) << 2) | 2ull,
                __ATOMIC_RELEASE, __HIP_MEMORY_SCOPE_AGENT);
        }
        sprefix = prefix;
    }
    __syncthreads();
    int base = sprefix;
    if (i < N) row_start[i] = base + incl - c;
    if (bid == nb - 1 && t == 255) row_start[N] = base + aggregate;
}

// ---------------- fp16 MFMA GEMM body + fused attention dots ---------------

template<int K, int NN, int H, bool ATOMIC>
__device__ void gemm_body(int bx, int M,
        const __half* __restrict__ A, const __half* __restrict__ Bp,
        const float* __restrict__ att_s, const float* __restrict__ att_d,
        float* __restrict__ as_, float* __restrict__ ad_,
        __half* __restrict__ Hout) {
    constexpr int KS = K >> 5;
    constexpr int CW = NN / 64;            // waves across columns
    constexpr int RW = 4 / CW;             // row-wave groups per block
    constexpr int C = NN / H;              // channels per head
    const int lane = threadIdx.x & 63;
    const int w = threadIdx.x >> 6;
    const int wr = w / CW;
    const int wc = w % CW;
    const int quad = lane >> 4;
    const int r16 = lane & 15;
    const int mBase = bx * (RW * 32) + wr * 32;
    const int nBase = wc * 64;
    const int head = nBase / C;

    f32x4 acc[2][4];
#pragma unroll
    for (int rt = 0; rt < 2; ++rt)
#pragma unroll
        for (int ct = 0; ct < 4; ++ct) acc[rt][ct] = (f32x4){0.f, 0.f, 0.f, 0.f};

#pragma unroll
    for (int ks = 0; ks < KS; ++ks) {
        f16x8 af[2];
#pragma unroll
        for (int rt = 0; rt < 2; ++rt) {
            int row = mBase + rt * 16 + r16;
            if (row < M) {
                size_t off = (size_t)row * K + ks * 32 + quad * 8;
                af[rt] = *(const f16x8*)(A + off);
            } else {
                af[rt] = (f16x8){0,0,0,0,0,0,0,0};
            }
        }
        f16x8 bf[4];
#pragma unroll
        for (int ct = 0; ct < 4; ++ct) {
            int ctg = (nBase >> 4) + ct;
            size_t off = ((size_t)(ctg * KS + ks) * 64 + lane) * 8;
            bf[ct] = *(const f16x8*)(Bp + off);
        }
#pragma unroll
        for (int rt = 0; rt < 2; ++rt)
#pragma unroll
            for (int ct = 0; ct < 4; ++ct)
                acc[rt][ct] = __builtin_amdgcn_mfma_f32_16x16x32_f16(af[rt], bf[ct], acc[rt][ct], 0, 0, 0);
    }

    // store h (fp16); C/D layout: lane l reg r -> row=(l>>4)*4+r, col=l&15
#pragma unroll
    for (int rt = 0; rt < 2; ++rt)
#pragma unroll
        for (int ct = 0; ct < 4; ++ct) {
            int row0 = mBase + rt * 16 + quad * 4;
            int col = nBase + ct * 16 + r16;
#pragma unroll
            for (int r = 0; r < 4; ++r) {
                int row = row0 + r;
                if (row < M) Hout[(size_t)row * NN + col] = __float2half(acc[rt][ct][r]);
            }
        }

    // fused attention dots
    float attS[4], attD[4];
#pragma unroll
    for (int ct = 0; ct < 4; ++ct) {
        int cc = (nBase % C) + ct * 16 + r16;   // channel within head
        attS[ct] = att_s[head * C + cc];
        attD[ct] = att_d[head * C + cc];
    }
#pragma unroll
    for (int rt = 0; rt < 2; ++rt)
#pragma unroll
        for (int r = 0; r < 4; ++r) {
            float ps = 0.f, pd = 0.f;
#pragma unroll
            for (int ct = 0; ct < 4; ++ct) {
                ps += acc[rt][ct][r] * attS[ct];
                pd += acc[rt][ct][r] * attD[ct];
            }
#pragma unroll
            for (int off = 1; off < 16; off <<= 1) {
                ps += __shfl_xor(ps, off);
                pd += __shfl_xor(pd, off);
            }
            int row = mBase + rt * 16 + quad * 4 + r;
            if (r16 == 0 && row < M) {
                if (ATOMIC) {
                    atomicAdd(&as_[row * H + head], ps);
                    atomicAdd(&ad_[row * H + head], pd);
                } else {
                    as_[row * H + head] = ps;
                    ad_[row * H + head] = pd;
                }
            }
        }
}

template<int K, int NN, int H, bool ATOMIC>
__global__ __launch_bounds__(256) void mfma_gemm(int M,
        const __half* __restrict__ A, const __half* __restrict__ Bp,
        const float* __restrict__ att_s, const float* __restrict__ att_d,
        float* __restrict__ as_, float* __restrict__ ad_,
        __half* __restrict__ Hout) {
    gemm_body<K, NN, H, ATOMIC>(blockIdx.x, M, A, Bp, att_s, att_d, as_, ad_, Hout);
}

// ---------------- fused atomic-free fill + layer-1 GEMM --------------------
// Blocks [0, FB): pos = row_start[d] + rank[e] scatter (no atomic round-trip,
// retires fast). Blocks [FB, FB+G1B): gemm1. Independent work, one dispatch.

__global__ __launch_bounds__(256) void fill_gemm1(
        int FB, const int* __restrict__ ei, int E, int N,
        const int* __restrict__ row_start, const int* __restrict__ rank,
        int* __restrict__ csr_src,
        const __half* __restrict__ A, const __half* __restrict__ Bp,
        const float* __restrict__ att_s, const float* __restrict__ att_d,
        float* __restrict__ as_, float* __restrict__ ad_,
        __half* __restrict__ Hout) {
    if ((int)blockIdx.x < FB) {
        int e = blockIdx.x * 256 + threadIdx.x;
        int Etot = E + N;
        if (e >= Etot) return;
        int s, d;
        if (e < E) { s = ei[e]; d = ei[E + e]; } else { s = e - E; d = s; }
        csr_src[row_start[d] + rank[e]] = s;
        return;
    }
    gemm_body<128, 256, 4, false>(blockIdx.x - FB, N, A, Bp,
                                  att_s, att_d, as_, ad_, Hout);
}

// ---------------- fused CSR softmax + aggregate (fp16 gather) ----------------
// 256-thread block = 4 independent waves, wave w handles node blk*4+w.

__device__ inline float edge_w(float a) {
    float e = a > 0.f ? a : NEG_SLOPE * a;
    return __expf(e);
}

template<int U, int HC, int H, int GRP>
__device__ inline void agg_step(int p, const int* __restrict__ csr_src,
                                const __half* __restrict__ h,
                                const float* __restrict__ as_, float adv,
                                int c0, int head, float* acc, float& den) {
    int srcv[U];
#pragma unroll
    for (int u = 0; u < U; ++u) srcv[u] = csr_src[p + u * GRP];
    float f[U][8];
#pragma unroll
    for (int u = 0; u < U; ++u) loadH8(f[u], h + (size_t)srcv[u] * HC + c0);
    float wv[U];
#pragma unroll
    for (int u = 0; u < U; ++u) wv[u] = edge_w(as_[srcv[u] * H + head] + adv);
#pragma unroll
    for (int u = 0; u < U; ++u) den += wv[u];
#pragma unroll
    for (int u = 0; u < U; ++u)
#pragma unroll
        for (int i = 0; i < 8; ++i) acc[i] += wv[u] * f[u][i];
}

template<int HC, int H, bool F16OUT>
__global__ __launch_bounds__(256) void fused_agg(int N,
                                                 const int* __restrict__ row_start,
                                                 const int* __restrict__ csr_src,
                                                 const __half* __restrict__ h,
                                                 const float* __restrict__ as_,
                                                 const float* __restrict__ ad_,
                                                 const float* __restrict__ bias,
                                                 float* __restrict__ out,
                                                 __half* __restrict__ outh) {
    constexpr int LPE = HC / 8;          // lanes per edge (32 or 16)
    constexpr int GRP = 64 / LPE;        // concurrent edges per wave (2 or 4)
    constexpr int C = HC / H;
    const int n = blockIdx.x * 4 + (threadIdx.x >> 6);
    if (n >= N) return;
    const int lane = threadIdx.x & 63;
    const int g = lane / LPE;
    const int lq = lane % LPE;
    const int c0 = lq * 8;
    const int head = c0 / C;
    const int s0 = row_start[n], s1 = row_start[n + 1];
    const float adv = ad_[n * H + head];
    float acc[8] = {};
    float den = 0.f;
    int p = s0 + g;
    for (; p + 3 * GRP < s1; p += 4 * GRP)
        agg_step<4, HC, H, GRP>(p, csr_src, h, as_, adv, c0, head, acc, den);
    for (; p < s1; p += GRP)
        agg_step<1, HC, H, GRP>(p, csr_src, h, as_, adv, c0, head, acc, den);
#pragma unroll
    for (int off = LPE; off < 64; off <<= 1) {
        den += __shfl_xor(den, off);
#pragma unroll
        for (int i = 0; i < 8; ++i) acc[i] += __shfl_xor(acc[i], off);
    }
    if (g == 0) {
        float dinv = 1.0f / (den + 1e-16f);
        float o[8];
#pragma unroll
        for (int i = 0; i < 8; ++i) {
            float v = acc[i] * dinv + bias[c0 + i];
            o[i] = v > 0.f ? v : 0.f;
        }
        if (F16OUT) {
            union { s16x8 raw; __half hv[8]; } u;
#pragma unroll
            for (int i = 0; i < 8; ++i) u.hv[i] = __float2half(o[i]);
            *(s16x8*)(outh + (size_t)n * HC + c0) = u.raw;
        } else {
            float4 v0 = make_float4(o[0], o[1], o[2], o[3]);
            float4 v1 = make_float4(o[4], o[5], o[6], o[7]);
            *(float4*)(out + (size_t)n * HC + c0) = v0;
            *(float4*)(out + (size_t)n * HC + c0 + 4) = v1;
        }
    }
}

extern "C" void kernel_launch(void* const* d_in, const int* in_sizes, int n_in,
                              void* d_out, int out_size, void* d_ws, size_t ws_size,
                              hipStream_t stream) {
    const float* x      = (const float*)d_in[0];
    const int*   ei     = (const int*)d_in[1];
    const float* W1     = (const float*)d_in[2];
    const float* att_s1 = (const float*)d_in[3];
    const float* att_d1 = (const float*)d_in[4];
    const float* b1     = (const float*)d_in[5];
    const float* W2     = (const float*)d_in[6];
    const float* att_s2 = (const float*)d_in[7];
    const float* att_d2 = (const float*)d_in[8];
    const float* b2     = (const float*)d_in[9];
    float* out = (float*)d_out;

    const int N_ = in_sizes[0] / 128;   // 50000
    const int E_ = in_sizes[1] / 2;     // 800000
    const int Etot = E_ + N_;           // 850000

    // workspace layout
    __half* h1 = (__half*)d_ws;                              // N*256 fp16 (also h2)
    __half* x2 = h1 + (size_t)N_ * 256;                      // N*256 fp16
    __half* xf = x2;                                         // N*128 fp16 (overlay:
                                                             // xf dead before agg1 writes x2)
    __half* bp1 = x2 + (size_t)N_ * 256;                     // 32768 fp16
    __half* bp2 = bp1 + 32768;                               // 32768 fp16
    float* as1 = (float*)(bp2 + 32768);                      // N*4
    float* ad1 = as1 + (size_t)N_ * 4;                       // N*4
    // ---- contiguous zero region (one memset): cnt | as2 | ad2 | bcount+pad | status
    int*   cnt    = (int*)(ad1 + (size_t)N_ * 4);            // N
    float* as2    = (float*)(cnt + N_);                      // N
    float* ad2    = as2 + N_;                                // N
    int*   bcount = (int*)(ad2 + N_);                        // 1 (+1 pad)
    unsigned long long* status = (unsigned long long*)(bcount + 2);  // 256
    size_t zeroBytes = (size_t)(3 * N_ + 2) * 4 + 256 * 8;
    // ---- end zero region
    int* row_start = (int*)(status + 256);                   // N+1
    int* rank      = row_start + (N_ + 1);                   // Etot
    int* csr_src   = rank + Etot;                            // Etot

    int nb = (N_ + 255) / 256;          // 196 scan blocks
    int FB = (Etot + 255) / 256;        // 3321 fill blocks
    int G1B = (N_ + 31) / 32;           // 1563 gemm1 blocks
    int nx = N_ * 128;

    hipMemsetAsync(cnt, 0, zeroBytes, stream);
    prep_kernel<<<(nx + 255) / 256, 256, 0, stream>>>(
        x, xf, nx, W1, bp1, W2, bp2, ei, E_, cnt, rank, N_);
    scan_chained<<<nb, 256, 0, stream>>>(cnt, row_start, status, bcount, N_, nb);

    // ---- layer 1: fill CSR + GEMM (128 -> 4x64) in one dispatch ----
    fill_gemm1<<<FB + G1B, 256, 0, stream>>>(
        FB, ei, E_, N_, row_start, rank, csr_src,
        xf, bp1, att_s1, att_d1, as1, ad1, h1);
    fused_agg<256, 4, true><<<(N_ + 3) / 4, 256, 0, stream>>>(
        N_, row_start, csr_src, h1, as1, ad1, b1, nullptr, x2);

    // ---- layer 2: 256 -> 1x128 ----
    __half* h2 = h1;  // reuse
    mfma_gemm<256, 128, 1, true><<<(N_ + 63) / 64, 256, 0, stream>>>(
        N_, x2, bp2, att_s2, att_d2, as2, ad2, h2);
    fused_agg<128, 1, false><<<(N_ + 3) / 4, 256, 0, stream>>>(
        N_, row_start, csr_src, h2, as2, ad2, b2, out, nullptr);

    (void)n_in; (void)out_size; (void)ws_size;
}